// Round 5
// baseline (1054.921 us; speedup 1.0000x reference)
//
#include <hip/hip_runtime.h>

typedef unsigned int u32;
typedef unsigned short u16;
typedef __bf16 bf16x8 __attribute__((ext_vector_type(8)));
typedef float f32x16 __attribute__((ext_vector_type(16)));
typedef float f32x4v __attribute__((ext_vector_type(4)));
typedef u32 u32x4 __attribute__((ext_vector_type(4)));
typedef u32 u32x2 __attribute__((ext_vector_type(2)));

#define BATCH    32768
#define DIN      256
#define UNITS    512
#define BM       32
#define NTHREADS 1024
#define NSTEP    6
#define DT       (1.0f/6.0f)

__device__ __forceinline__ u16 f2bf(float f) {
  return __builtin_bit_cast(u16, (__bf16)f);
}
__device__ __forceinline__ float bf2f(u16 b) {
  return __builtin_bit_cast(float, (u32)b << 16);
}
__device__ __forceinline__ u32 pk2(float a, float b) {
  return (u32)f2bf(a) | ((u32)f2bf(b) << 16);
}
__device__ __forceinline__ float fast_tanh(float x) {
  float t = fminf(fmaxf(x * 2.885390082f, -60.f), 60.f);
  float a = __builtin_amdgcn_exp2f(t);
  return (a - 1.f) * __builtin_amdgcn_rcpf(a + 1.f);
}

// Pack K (256x512) and R (512x512) f32 row-major into bf16 B-fragment order:
// chunk c = g*512 + n holds rows g*8..g*8+7, col n (16B per lane).
__global__ void pack_weights(const float* __restrict__ Km, const float* __restrict__ Rm,
                             u16* __restrict__ Kp, u16* __restrict__ Rp) {
  int c = blockIdx.x * 256 + threadIdx.x;          // 0 .. 49151
  if (c < 32768) {
    int n = c & 511, g = c >> 9;                   // g < 64
    u32x4 p;
#pragma unroll
    for (int i = 0; i < 4; ++i) {
      u16 lo = f2bf(Rm[(g * 8 + 2 * i) * 512 + n]);
      u16 hh = f2bf(Rm[(g * 8 + 2 * i + 1) * 512 + n]);
      p[i] = (u32)lo | ((u32)hh << 16);
    }
    ((u32x4*)Rp)[c] = p;
  } else {
    int c2 = c - 32768;                            // < 16384
    int n = c2 & 511, g = c2 >> 9;                 // g < 32
    u32x4 p;
#pragma unroll
    for (int i = 0; i < 4; ++i) {
      u16 lo = f2bf(Km[(g * 8 + 2 * i) * 512 + n]);
      u16 hh = f2bf(Km[(g * 8 + 2 * i + 1) * 512 + n]);
      p[i] = (u32)lo | ((u32)hh << 16);
    }
    ((u32x4*)Kp)[c2] = p;
  }
}

__global__ __launch_bounds__(NTHREADS, 8)
void ctrnn_fused(const float* __restrict__ X, const float* __restrict__ H0,
                 const u16* __restrict__ Kp, const u16* __restrict__ Rp,
                 const float* __restrict__ bias, const float* __restrict__ scale,
                 float* __restrict__ out) {
  // Double-buffered he: 2 x 32KB [32 rows][512 cols] bf16, pitch 1024B,
  // swizzle ^((m&7)<<4). Prologue stages x in buf0 ([32][256], pitch 512B).
  __shared__ char heL[2][32768];

  const int tid  = threadIdx.x;
  const int lane = tid & 63;
  const int wv   = tid >> 6;             // 0..15 — wave owns cols [wv*32, wv*32+32)
  const int ln   = lane & 31, hi = lane >> 5;
  const long r0  = (long)blockIdx.x * BM;

  const int jc  = wv * 32 + ln;          // this thread's output column
  const int swA = (ln & 7) << 4;

  // stage x tile -> bf16 LDS buf0 [32][256], pitch 512B
  {
    const f32x4v* X4 = (const f32x4v*)(X + r0 * DIN);
#pragma unroll
    for (int i = 0; i < 2; ++i) {
      int flat = i * NTHREADS + tid;     // 0..2047 float4-chunks
      int m = flat >> 6, c4 = flat & 63;
      f32x4v v = X4[m * 64 + c4];
      u32x2 p;
      p.x = pk2(v.x, v.y);
      p.y = pk2(v.z, v.w);
      *(u32x2*)(heL[0] + m * 512 + ((c4 * 8) ^ ((m & 7) << 4))) = p;
    }
  }

  const float scl = scale[jc];

  __syncthreads();

  // ---- prologue: xkb = x @ K + bias -> packed bf16 in regs (xkbP) ----
  u32 xkbP[8];
  {
    f32x16 pre;
    {
      float b = bias[jc];
#pragma unroll
      for (int r = 0; r < 16; ++r) pre[r] = b;
    }
    const u32x4* Kp4 = (const u32x4*)Kp;
#pragma unroll 2
    for (int kb = 0; kb < 16; ++kb) {
      bf16x8 a = __builtin_bit_cast(bf16x8,
          *(const u32x4*)(heL[0] + ln * 512 + (((kb * 32) | (hi * 16)) ^ swA)));
      bf16x8 b = __builtin_bit_cast(bf16x8, Kp4[(kb * 2 + hi) * 512 + jc]);
      pre = __builtin_amdgcn_mfma_f32_32x32x16_bf16(a, b, pre, 0, 0, 0);
    }
#pragma unroll
    for (int i = 0; i < 8; ++i)
      xkbP[i] = pk2(pre[2 * i], pre[2 * i + 1]);
  }

  // load h (f32) in C-fragment layout
  float h[16];
  u32 accP[8];
#pragma unroll
  for (int r = 0; r < 16; ++r) {
    int m = (r & 3) + ((r >> 2) << 3) + hi * 4;
    h[r] = H0[(r0 + m) * UNITS + jc];
  }

  __syncthreads();   // prologue reads of x-region done; buf0 becomes he buffer

  // write he_1 = bf16(h) into buf0
#pragma unroll
  for (int r = 0; r < 16; ++r) {
    int m = (r & 3) + ((r >> 2) << 3) + hi * 4;
    *(u16*)(heL[0] + m * 1024 + ((jc * 2) ^ ((m & 7) << 4))) = f2bf(h[r]);
  }
  __syncthreads();

  const u32x4* Rp4 = (const u32x4*)Rp;
  int p = 0;   // current he buffer

  for (int step = 0; step < NSTEP; ++step) {
#pragma unroll
    for (int ev = 0; ev < 4; ++ev) {
      // pre = xkb (register unpack)
      f32x16 pre;
#pragma unroll
      for (int i = 0; i < 8; ++i) {
        pre[2 * i]     = bf2f((u16)(xkbP[i] & 0xffffu));
        pre[2 * i + 1] = bf2f((u16)(xkbP[i] >> 16));
      }
      // pre += he @ R  (32 k-blocks; B frags streamed from L2)
#pragma unroll 2
      for (int kb = 0; kb < 32; ++kb) {
        bf16x8 a = __builtin_bit_cast(bf16x8,
            *(const u32x4*)(heL[p] + ln * 1024 + (((kb * 32) | (hi * 16)) ^ swA)));
        bf16x8 b = __builtin_bit_cast(bf16x8, Rp4[(kb * 2 + hi) * 512 + jc]);
        pre = __builtin_amdgcn_mfma_f32_32x32x16_bf16(a, b, pre, 0, 0, 0);
      }

      // epilogue: k = scale*tanh(pre) - he_i ; RK4 bookkeeping.
      // he_i re-read from buf[p] (2 lanes/bank same-dword -> conflict-free);
      // he_next written to buf[p^1] (read-complete since last barrier).
      const float wk = (ev == 1 || ev == 2) ? 2.f : 1.f;
      const float ce = (ev < 2) ? (DT * 0.5f) : DT;
      const bool last = (step == NSTEP - 1) && (ev == 3);
#pragma unroll
      for (int rp = 0; rp < 8; ++rp) {
        float k01[2];
#pragma unroll
        for (int half = 0; half < 2; ++half) {
          int r = rp * 2 + half;
          int m = (r & 3) + ((r >> 2) << 3) + hi * 4;
          float hev = bf2f(*(const u16*)(heL[p] + m * 1024 + ((jc * 2) ^ ((m & 7) << 4))));
          k01[half] = scl * fast_tanh(pre[r]) - hev;
        }
        float a0 = (ev == 0 ? 0.f : bf2f((u16)(accP[rp] & 0xffffu))) + wk * k01[0];
        float a1 = (ev == 0 ? 0.f : bf2f((u16)(accP[rp] >> 16)))     + wk * k01[1];
        float n0, n1;
        if (ev == 3) {
          h[2 * rp]     += (DT / 6.f) * a0;
          h[2 * rp + 1] += (DT / 6.f) * a1;
          n0 = h[2 * rp];
          n1 = h[2 * rp + 1];
        } else {
          accP[rp] = pk2(a0, a1);
          n0 = h[2 * rp]     + ce * k01[0];
          n1 = h[2 * rp + 1] + ce * k01[1];
        }
        if (!last) {
#pragma unroll
          for (int half = 0; half < 2; ++half) {
            int r = rp * 2 + half;
            int m = (r & 3) + ((r >> 2) << 3) + hi * 4;
            *(u16*)(heL[p ^ 1] + m * 1024 + ((jc * 2) ^ ((m & 7) << 4))) =
                f2bf(half ? n1 : n0);
          }
        }
      }
      p ^= 1;
      __syncthreads();   // he_{i+1} visible; prev buffer free for overwrite
    }
  }

  // store final h
#pragma unroll
  for (int r = 0; r < 16; ++r) {
    int m = (r & 3) + ((r >> 2) << 3) + hi * 4;
    out[(r0 + m) * UNITS + jc] = h[r];
  }
}

extern "C" void kernel_launch(void* const* d_in, const int* in_sizes, int n_in,
                              void* d_out, int out_size, void* d_ws, size_t ws_size,
                              hipStream_t stream) {
  const float* X     = (const float*)d_in[0];
  const float* H0    = (const float*)d_in[1];
  const float* Km    = (const float*)d_in[2];
  const float* Rm    = (const float*)d_in[3];
  const float* bias  = (const float*)d_in[4];
  const float* scale = (const float*)d_in[5];
  float* out = (float*)d_out;

  u16* Rp = (u16*)d_ws;                  // 512*512 bf16 = 512KB
  u16* Kp = Rp + UNITS * UNITS;          // 256*512 bf16 = 256KB

  pack_weights<<<192, 256, 0, stream>>>(Km, Rm, Kp, Rp);
  ctrnn_fused<<<BATCH / BM, NTHREADS, 0, stream>>>(X, H0, Kp, Rp, bias, scale, out);
}